// Round 7
// baseline (169.877 us; speedup 1.0000x reference)
//
#include <hip/hip_runtime.h>

// GCN aggregation: out[t] = norm[t] * sum_{e:dst=t} norm[src]*x[src] + EPS*x[t]
// Round 16: parallelism fixes in all three kernels (round-15 evidence:
// sortgather Occupancy 28.5% because grid NB=391 blocks ~ 1.5/CU; partition+
// normyh ~ 104 us combined, both grid/latency-starved).
// (a) sortgather: 2 blocks per bucket (grid 2*NB=782). Both halves copy+sort
//     the bucket's records; each gathers a disjoint 128-node half. hist/rank/
//     scan shrink to 128 entries. Occupancy ceiling 38% -> 76%.
// (b) normyh: 512 threads; tabS column preloaded into LDS (parallel loads, no
//     dependent chain), then 8-lane groups stream srec bytes -> LDS hist.
// (c) partition: histD/histS packed into one u32 (low=D, high=S; counts<=4096
//     so halves never carry) -> single packed scan, half the barriers/LDS.
// 3 launches, no memset.
constexpr int D        = 64;
constexpr float EPS    = 0.5f;
constexpr int BKT      = 256;    // nodes per bucket
constexpr int HBKT     = 128;    // nodes per sortgather half-block
constexpr int CAPB     = 4096;   // sortgather LDS chunk capacity (records)
constexpr int EPB      = 4096;   // edges per partition block (= region stride)
constexpr int PTHREADS = 512;
constexpr int EPT      = EPB / PTHREADS;   // 8
constexpr int GTHREADS = 512;    // sortgather block size (8 waves)
constexpr int NTHREADS = 512;    // normyh block size
constexpr int NBMAX    = 512;    // max node buckets (n <= 131072)
constexpr int MAXBLK   = 512;    // max partition blocks (E <= 2M)

__device__ __forceinline__ unsigned int f2bf(float f) {
    unsigned int u = __float_as_uint(f);
    return (u + 0x7FFFu + ((u >> 16) & 1u)) >> 16;   // RNE to bf16
}
__device__ __forceinline__ float bf2f_lo(unsigned int v) { return __uint_as_float(v << 16); }
__device__ __forceinline__ float bf2f_hi(unsigned int v) { return __uint_as_float(v & 0xFFFF0000u); }

// ---------------- main path ----------------

// Each block owns edges [blk*EPB, blk*EPB+cnt) and its own output region.
// Writes: recB[blk][i] (u32, sorted by dst-bucket), srecB[blk][i] (u8, sorted
// by src-bucket), tabD/tabS[blk][0..NB] = exclusive scan (u16). All streaming.
__global__ __launch_bounds__(PTHREADS)
void partition_kernel(const int* __restrict__ src, const int* __restrict__ dst,
                      unsigned int* __restrict__ recB, unsigned char* __restrict__ srecB,
                      unsigned short* __restrict__ tabD, unsigned short* __restrict__ tabS,
                      int E, int NB, int NBP) {
    __shared__ unsigned int  srt[EPB];      // 16 KB sorted dst-records
    __shared__ unsigned char ssrt[EPB];     // 4 KB sorted src bytes
    __shared__ unsigned int histDS[NBMAX];  // low16 = D count, high16 = S count; reused as rank
    __shared__ unsigned int rsDS[NBMAX];    // packed exclusive scans
    __shared__ unsigned int wsums[PTHREADS / 64];
    __shared__ unsigned int carry;

    const int blk  = blockIdx.x;
    const int base = blk * EPB;
    const int tid  = threadIdx.x;
    const int lane = tid & 63;
    const int wid  = tid >> 6;
    const int cnt  = min(EPB, E - base);
    const bool full = (cnt == EPB);

    for (int b = tid; b < NB; b += PTHREADS) histDS[b] = 0;
    __syncthreads();

    // ---- pass 1: count per bucket (packed) ----
    if (full) {
        const int4* s4 = (const int4*)(src + base);
        const int4* d4 = (const int4*)(dst + base);
        #pragma unroll
        for (int k = 0; k < EPT / 4; ++k) {
            int4 sv = s4[tid + k * PTHREADS];
            int4 dv = d4[tid + k * PTHREADS];
            atomicAdd(&histDS[dv.x >> 8], 1u); atomicAdd(&histDS[sv.x >> 8], 0x10000u);
            atomicAdd(&histDS[dv.y >> 8], 1u); atomicAdd(&histDS[sv.y >> 8], 0x10000u);
            atomicAdd(&histDS[dv.z >> 8], 1u); atomicAdd(&histDS[sv.z >> 8], 0x10000u);
            atomicAdd(&histDS[dv.w >> 8], 1u); atomicAdd(&histDS[sv.w >> 8], 0x10000u);
        }
    } else {
        for (int k = 0; k < EPT; ++k) {
            int e = tid + k * PTHREADS;
            if (e < cnt) {
                atomicAdd(&histDS[dst[base + e] >> 8], 1u);
                atomicAdd(&histDS[src[base + e] >> 8], 0x10000u);
            }
        }
    }
    __syncthreads();

    // ---- packed exclusive scan histDS -> rsDS (halves scan independently) ----
    if (tid == 0) carry = 0;
    __syncthreads();
    for (int bp = 0; bp < NB; bp += PTHREADS) {
        int idx = bp + tid;
        unsigned int orig = (idx < NB) ? histDS[idx] : 0u;
        if (idx < NB) histDS[idx] = 0;
        unsigned int v = orig;
        #pragma unroll
        for (int off = 1; off < 64; off <<= 1) {
            unsigned int t = __shfl_up(v, off);
            if (lane >= off) v += t;
        }
        if (lane == 63) wsums[wid] = v;
        __syncthreads();
        unsigned int add = carry;
        for (int w = 0; w < wid; ++w) add += wsums[w];
        if (idx < NB) rsDS[idx] = v - orig + add;
        __syncthreads();
        if (tid == 0) {
            unsigned int s = carry;
            for (int w = 0; w < PTHREADS / 64; ++w) s += wsums[w];
            carry = s;
        }
        __syncthreads();
    }

    // ---- write prefix tables (coalesced u16) ----
    for (int b = tid; b <= NB; b += PTHREADS) {
        unsigned int v = (b < NB) ? rsDS[b] : ((unsigned int)cnt | ((unsigned int)cnt << 16));
        tabD[(size_t)blk * NBP + b] = (unsigned short)(v & 0xFFFFu);
        tabS[(size_t)blk * NBP + b] = (unsigned short)(v >> 16);
    }

    // ---- pass 2: place into LDS sorted position ----
    if (full) {
        const int4* s4 = (const int4*)(src + base);
        const int4* d4 = (const int4*)(dst + base);
        #pragma unroll
        for (int k = 0; k < EPT / 4; ++k) {
            int4 sv = s4[tid + k * PTHREADS];
            int4 dv = d4[tid + k * PTHREADS];
            int ss[4] = {sv.x, sv.y, sv.z, sv.w};
            int tt[4] = {dv.x, dv.y, dv.z, dv.w};
            #pragma unroll
            for (int j = 0; j < 4; ++j) {
                int s = ss[j], t = tt[j];
                int bD = t >> 8;
                unsigned int r = atomicAdd(&histDS[bD], 1u) & 0xFFFFu;
                srt[(rsDS[bD] & 0xFFFFu) + r] = ((unsigned int)s << 8) | (unsigned int)(t & (BKT - 1));
                int bS = s >> 8;
                unsigned int r2 = atomicAdd(&histDS[bS], 0x10000u) >> 16;
                ssrt[(rsDS[bS] >> 16) + r2] = (unsigned char)(s & (BKT - 1));
            }
        }
    } else {
        for (int k = 0; k < EPT; ++k) {
            int e = tid + k * PTHREADS;
            if (e < cnt) {
                int s = src[base + e], t = dst[base + e];
                int bD = t >> 8;
                unsigned int r = atomicAdd(&histDS[bD], 1u) & 0xFFFFu;
                srt[(rsDS[bD] & 0xFFFFu) + r] = ((unsigned int)s << 8) | (unsigned int)(t & (BKT - 1));
                int bS = s >> 8;
                unsigned int r2 = atomicAdd(&histDS[bS], 0x10000u) >> 16;
                ssrt[(rsDS[bS] >> 16) + r2] = (unsigned char)(s & (BKT - 1));
            }
        }
    }
    __syncthreads();

    // ---- pass 3: stream full region out (bytes beyond cnt are never read) ----
    {
        uint4* go = (uint4*)(recB + (size_t)blk * EPB);
        const uint4* gi = (const uint4*)srt;
        for (int i = tid; i < EPB / 4; i += PTHREADS) go[i] = gi[i];
        uint4* so = (uint4*)(srecB + (size_t)blk * EPB);
        const uint4* si = (const uint4*)ssrt;
        for (int i = tid; i < EPB / 16; i += PTHREADS) so[i] = si[i];
    }
}

// Per-bucket: out-degree histogram from srecB segments -> norm[] -> yh.
// Segment table preloaded into LDS (kills the tab->byte dependent chain);
// bytes read by 8-lane groups.
__global__ __launch_bounds__(NTHREADS)
void normyh_kernel(const unsigned char* __restrict__ srecB, const unsigned short* __restrict__ tabS,
                   const float2* __restrict__ x2, unsigned int* __restrict__ yh,
                   float* __restrict__ norm, int n, int NBLK, int NBP) {
    const int b   = blockIdx.x;
    const int tid = threadIdx.x;
    __shared__ unsigned int segO[MAXBLK];      // o0 | o1<<16
    __shared__ int hist[BKT];
    __shared__ float nrm[BKT];
    if (tid < BKT) hist[tid] = 0;
    for (int blk = tid; blk < NBLK; blk += NTHREADS) {
        unsigned int o0 = tabS[(size_t)blk * NBP + b];
        unsigned int o1 = tabS[(size_t)blk * NBP + b + 1];
        segO[blk] = o0 | (o1 << 16);
    }
    __syncthreads();
    const int g  = tid >> 3;                   // 64 groups of 8 lanes
    const int gl = tid & 7;
    for (int blk = g; blk < NBLK; blk += NTHREADS / 8) {
        unsigned int u = segO[blk];
        int o0 = (int)(u & 0xFFFFu), o1 = (int)(u >> 16);
        const unsigned char* p = srecB + (size_t)blk * EPB;
        for (int j = o0 + gl; j < o1; j += 8) atomicAdd(&hist[p[j]], 1);
    }
    __syncthreads();
    if (tid < BKT) {
        int node = b * BKT + tid;
        float nm = rsqrtf(fmaxf((float)hist[tid], 1.0f));
        nrm[tid] = nm;
        if (node < n) norm[node] = nm;
    }
    __syncthreads();
    int nodes = n - b * BKT;
    if (nodes > BKT) nodes = BKT;
    if (nodes < 0) nodes = 0;
    int total = nodes * (D / 2);               // float2 elements in this bucket
    size_t gbase = (size_t)b * BKT * (D / 2);
    for (int i = tid; i < total; i += NTHREADS) {   // contiguous -> coalesced
        float2 v = x2[gbase + i];
        float nm2 = nrm[i >> 5];
        yh[gbase + i] = f2bf(v.x * nm2) | (f2bf(v.y * nm2) << 16);
    }
}

// TWO blocks per bucket (grid 2*NB): both copy+sort the bucket's records from
// the per-block segments; each gathers a disjoint 128-node half (hist/rank/
// scan are 128-entry). 512 threads, ~38 KB LDS -> 4 blocks/CU; occupancy
// ceiling 76% at NB=391. Chunked if cnt > CAPB (rare).
__global__ __launch_bounds__(GTHREADS)
void sortgather_kernel(const unsigned int* __restrict__ recB, const unsigned short* __restrict__ tabD,
                       const float* __restrict__ norm, const uint4* __restrict__ yr4,
                       const float4* __restrict__ x4, float4* __restrict__ out4,
                       int n, int NBLK, int NBP) {
    __shared__ unsigned int recs[CAPB];        // 16 KB
    __shared__ unsigned int srcs[CAPB];        // 16 KB
    __shared__ unsigned short segoff[MAXBLK];  // 1 KB
    __shared__ unsigned int dstoff[MAXBLK + 1];// 2 KB (len -> exclusive scan)
    __shared__ int hist[HBKT];
    __shared__ int rankb[HBKT];
    __shared__ int rsL[HBKT];
    __shared__ float nrmL[HBKT];
    __shared__ unsigned int wsums[GTHREADS / 64];
    __shared__ unsigned int carry;
    const int b     = blockIdx.x >> 1;
    const int half  = blockIdx.x & 1;
    const int hbase = half * HBKT;             // node offset within bucket
    const int tid   = threadIdx.x;
    const int lane  = tid & 63;
    const int wid   = tid >> 6;

    // segment table for this bucket
    for (int blk = tid; blk < NBLK; blk += GTHREADS) {
        unsigned int o0 = tabD[(size_t)blk * NBP + b];
        unsigned int o1 = tabD[(size_t)blk * NBP + b + 1];
        segoff[blk] = (unsigned short)o0;
        dstoff[blk] = o1 - o0;                 // length; scanned in place below
    }
    if (tid < HBKT) {
        int node = b * BKT + hbase + tid;
        nrmL[tid] = (node < n) ? norm[node] : 1.0f;
    }
    if (tid == 0) carry = 0;
    __syncthreads();
    // in-place exclusive scan of dstoff[0..NBLK)
    for (int bp = 0; bp < NBLK; bp += GTHREADS) {
        int idx = bp + tid;
        unsigned int orig = (idx < NBLK) ? dstoff[idx] : 0u;
        unsigned int v = orig;
        #pragma unroll
        for (int off = 1; off < 64; off <<= 1) {
            unsigned int t = __shfl_up(v, off);
            if (lane >= off) v += t;
        }
        if (lane == 63) wsums[wid] = v;
        __syncthreads();
        unsigned int add = carry;
        for (int w = 0; w < wid; ++w) add += wsums[w];
        if (idx < NBLK) dstoff[idx] = v - orig + add;
        __syncthreads();
        if (tid == 0) {
            unsigned int s = carry;
            for (int w = 0; w < GTHREADS / 64; ++w) s += wsums[w];
            carry = s;
        }
        __syncthreads();
    }
    if (tid == 0) dstoff[NBLK] = carry;
    __syncthreads();
    const int cnt = (int)dstoff[NBLK];
    const int nch = (cnt > CAPB) ? (cnt + CAPB - 1) / CAPB : 1;

    const int fl  = lane & 7;                  // uint4 index within 128B row
    const int oct = lane >> 3;                 // node within 8-node group

    for (int c = 0; c < nch; ++c) {
        const unsigned int lo = (unsigned int)c * CAPB;
        const unsigned int hi = min((unsigned int)cnt, lo + (unsigned int)CAPB);
        const int wlen = (int)(hi - lo);
        // copy window [lo,hi) into recs; 16-lane groups per segment
        {
            const int cg  = tid >> 4;
            const int cgl = tid & 15;
            for (int blk = cg; blk < NBLK; blk += GTHREADS / 16) {
                unsigned int dbase = dstoff[blk], dend = dstoff[blk + 1];
                unsigned int s0 = max(dbase, lo), s1 = min(dend, hi);
                if (s0 < s1) {
                    size_t glo = (size_t)blk * EPB + segoff[blk] + (s0 - dbase);
                    for (unsigned int j = cgl; j < s1 - s0; j += 16)
                        recs[s0 - lo + j] = recB[glo + j];
                }
            }
        }
        __syncthreads();                        // prev gather done + copy done
        if (tid < HBKT) hist[tid] = 0;
        __syncthreads();
        for (int i = tid; i < wlen; i += GTHREADS) {
            int ln = (int)(recs[i] & (BKT - 1));
            if ((ln >> 7) == half) atomicAdd(&hist[ln & (HBKT - 1)], 1);
        }
        __syncthreads();
        // scan hist[0..HBKT) (threads < 128 = 2 waves)
        {
            int v = (tid < HBKT) ? hist[tid] : 0;
            #pragma unroll
            for (int off = 1; off < 64; off <<= 1) {
                int t = __shfl_up(v, off);
                if (lane >= off) v += t;
            }
            if (tid < HBKT && lane == 63) wsums[wid] = (unsigned int)v;
            __syncthreads();
            if (tid < HBKT) {
                int add = (wid == 1) ? (int)wsums[0] : 0;
                int excl = v + add - hist[tid];
                rankb[tid] = excl;
                rsL[tid]   = excl;
            }
        }
        __syncthreads();
        for (int i = tid; i < wlen; i += GTHREADS) {
            unsigned int v = recs[i];
            int ln = (int)(v & (BKT - 1));
            if ((ln >> 7) == half) {
                int pos = atomicAdd(&rankb[ln & (HBKT - 1)], 1);
                srcs[pos] = v >> 8;
            }
        }
        __syncthreads();

        // ---- gather: 8 waves x 8 nodes -> 64 nodes/round, 2 rounds ----
        #pragma unroll
        for (int r = 0; r < HBKT / 64; ++r) {
            int ln   = r * 64 + wid * 8 + oct;  // 0..127 within half
            int node = b * BKT + hbase + ln;
            bool valid = node < n;
            int rsl = valid ? rsL[ln]  : 0;
            int cl  = valid ? hist[ln] : 0;
            int m = cl;                        // uniform loop count = wave-max
            m = max(m, __shfl_xor(m, 8));
            m = max(m, __shfl_xor(m, 16));
            m = max(m, __shfl_xor(m, 32));
            float a0 = 0.f, a1 = 0.f, a2 = 0.f, a3 = 0.f;
            float a4 = 0.f, a5 = 0.f, a6 = 0.f, a7 = 0.f;
            for (int k = 0; k < m; k += 8) {
                int sb[8];
                #pragma unroll
                for (int j = 0; j < 8; ++j) {  // 8 LDS reads issue together
                    int kj = k + j;
                    sb[j] = (kj < cl) ? (int)srcs[rsl + kj] : -1;
                }
                #pragma unroll
                for (int j = 0; j < 8; ++j) {  // 8 row loads in flight
                    bool take = sb[j] >= 0;
                    int s = take ? sb[j] : 0;  // dummy hits node 0's cached row
                    uint4 v = yr4[(size_t)s * 8 + fl];
                    if (!take) { v.x = 0u; v.y = 0u; v.z = 0u; v.w = 0u; }
                    a0 += bf2f_lo(v.x); a1 += bf2f_hi(v.x);
                    a2 += bf2f_lo(v.y); a3 += bf2f_hi(v.y);
                    a4 += bf2f_lo(v.z); a5 += bf2f_hi(v.z);
                    a6 += bf2f_lo(v.w); a7 += bf2f_hi(v.w);
                }
            }
            if (valid) {
                float nt = nrmL[ln];
                size_t basei = (size_t)node * 16 + fl * 2;
                float4 r0, r1;
                if (c == 0) {
                    float4 xv0 = x4[basei], xv1 = x4[basei + 1];
                    r0.x = a0 * nt + EPS * xv0.x;  r0.y = a1 * nt + EPS * xv0.y;
                    r0.z = a2 * nt + EPS * xv0.z;  r0.w = a3 * nt + EPS * xv0.w;
                    r1.x = a4 * nt + EPS * xv1.x;  r1.y = a5 * nt + EPS * xv1.y;
                    r1.z = a6 * nt + EPS * xv1.z;  r1.w = a7 * nt + EPS * xv1.w;
                } else {                       // rare multi-chunk path: RMW
                    float4 p0 = out4[basei], p1 = out4[basei + 1];
                    r0.x = p0.x + a0 * nt;  r0.y = p0.y + a1 * nt;
                    r0.z = p0.z + a2 * nt;  r0.w = p0.w + a3 * nt;
                    r1.x = p1.x + a4 * nt;  r1.y = p1.y + a5 * nt;
                    r1.z = p1.z + a6 * nt;  r1.w = p1.w + a7 * nt;
                }
                out4[basei] = r0;              // coalesced: 32B/lane
                out4[basei + 1] = r1;
            }
        }
    }
}

// ---------------- tiny-ws / big-n fallback (round-1 proven) ----------------

__global__ void fb_hist(const int* __restrict__ src, int* __restrict__ deg, int E) {
    int e = blockIdx.x * blockDim.x + threadIdx.x;
    if (e < E) atomicAdd(&deg[src[e]], 1);
}
__global__ void fb_norm(const int* __restrict__ deg, float* __restrict__ norm, int n) {
    int i = blockIdx.x * blockDim.x + threadIdx.x;
    if (i < n) norm[i] = rsqrtf(fmaxf((float)deg[i], 1.0f));
}
__global__ void fb_init_out(const float4* __restrict__ x, float4* __restrict__ out, int n4) {
    int i = blockIdx.x * blockDim.x + threadIdx.x;
    if (i < n4) {
        float4 v = x[i];
        out[i] = make_float4(v.x * EPS, v.y * EPS, v.z * EPS, v.w * EPS);
    }
}
__global__ void fb_scatter(const float* __restrict__ x, const int* __restrict__ src,
                           const int* __restrict__ dst, const float* __restrict__ norm,
                           float* __restrict__ out, int E) {
    long long tid = (long long)blockIdx.x * blockDim.x + threadIdx.x;
    int e = (int)(tid >> 6), d = (int)(tid & 63);
    if (e < E) {
        int s = src[e], t = dst[e];
        atomicAdd(&out[(size_t)t * D + d], norm[s] * norm[t] * x[(size_t)s * D + d]);
    }
}

// ---------------- launcher ----------------

extern "C" void kernel_launch(void* const* d_in, const int* in_sizes, int n_in,
                              void* d_out, int out_size, void* d_ws, size_t ws_size,
                              hipStream_t stream) {
    const float* x   = (const float*)d_in[0];
    const int*   src = (const int*)d_in[1];
    const int*   dst = (const int*)d_in[2];
    float* out = (float*)d_out;

    const int ND = in_sizes[0];
    const int E  = in_sizes[1];
    const int n  = ND / D;
    const int NB   = (n + BKT - 1) / BKT;
    const int NBLK = (E + EPB - 1) / EPB;
    const int NBP  = NB + 1;
    constexpr int B = 256;

    // workspace layout (16B-aligned chunks)
    size_t off = 0;
    auto take = [&](size_t bytes) { size_t o = off; off = (off + bytes + 15) & ~15ull; return o; };
    size_t o_rec  = take((size_t)NBLK * EPB * 4);       // recB u32
    size_t o_srec = take((size_t)NBLK * EPB);           // srecB u8
    size_t o_tabD = take((size_t)NBLK * NBP * 2);       // tabD u16
    size_t o_tabS = take((size_t)NBLK * NBP * 2);       // tabS u16
    size_t o_yh   = take((size_t)ND * 2);               // yh u32 (bf16x2)
    size_t o_norm = take((size_t)n * 4);                // norm f32
    size_t need = off;

    if (NB <= NBMAX && NBLK <= MAXBLK && n < (1 << 24) && need <= ws_size && E > 0) {
        char* ws = (char*)d_ws;
        unsigned int*   recB  = (unsigned int*)(ws + o_rec);
        unsigned char*  srecB = (unsigned char*)(ws + o_srec);
        unsigned short* tabD  = (unsigned short*)(ws + o_tabD);
        unsigned short* tabS  = (unsigned short*)(ws + o_tabS);
        unsigned int*   yh    = (unsigned int*)(ws + o_yh);
        float*          norm  = (float*)(ws + o_norm);

        partition_kernel<<<NBLK, PTHREADS, 0, stream>>>(src, dst, recB, srecB,
                                                        tabD, tabS, E, NB, NBP);
        normyh_kernel<<<NB, NTHREADS, 0, stream>>>(srecB, tabS, (const float2*)x, yh, norm,
                                                   n, NBLK, NBP);
        sortgather_kernel<<<2 * NB, GTHREADS, 0, stream>>>(recB, tabD, norm, (const uint4*)yh,
                                                           (const float4*)x, (float4*)out,
                                                           n, NBLK, NBP);
    } else {
        int*   deg  = (int*)d_ws;
        float* norm = (float*)d_ws + n;
        hipMemsetAsync(deg, 0, (size_t)n * sizeof(int), stream);
        fb_hist<<<(E + B - 1) / B, B, 0, stream>>>(src, deg, E);
        fb_norm<<<(n + B - 1) / B, B, 0, stream>>>(deg, norm, n);
        fb_init_out<<<(ND / 4 + B - 1) / B, B, 0, stream>>>((const float4*)x, (float4*)out, ND / 4);
        long long total = (long long)E * D;
        fb_scatter<<<(int)((total + B - 1) / B), B, 0, stream>>>(x, src, dst, norm, out, E);
    }
}

// Round 8
// 166.552 us; speedup vs baseline: 1.0200x; 1.0200x over previous
//
#include <hip/hip_runtime.h>

// GCN aggregation: out[t] = norm[t] * sum_{e:dst=t} norm[src]*x[src] + EPS*x[t]
// Round 17: right-size parallelism per phase. Evidence (r5-r7): partition+
// normyh ~ 95-105 us combined (both grid-starved: partition 306x512 = 1.2
// blocks/CU through ~10 barriers; normyh mixes latency-bound byte-hist with
// BW-bound 38 MB streaming in one 391-block grid). sortgather's 2-block split
// regressed (duplicated the serialized sort prologue): reverted to 1 block/
// bucket (known 62.5 us).
// (a) partition: 256 thr, EPB 2048 -> 611 blocks, ~13 KB LDS -> 8 blocks/CU.
// (b) degnorm: hist+norm only (NB blocks).
// (c) yhconv: pure streaming x->yh, grid-strided 2048 blocks -> full HBM BW.
// (d) sortgather: round-6 config, CAPB 3584 / MAXBLK 1024 (EPB halved ->
//     611 segments), 8-lane copy groups, 4 blocks/CU.
// 4 launches, no memset.
constexpr int D        = 64;
constexpr float EPS    = 0.5f;
constexpr int BKT      = 256;    // nodes per bucket
constexpr int CAPB     = 3584;   // sortgather LDS chunk capacity (records)
constexpr int EPB      = 2048;   // edges per partition block (= region stride)
constexpr int PTHREADS = 256;
constexpr int EPT      = EPB / PTHREADS;   // 8
constexpr int GTHREADS = 512;    // sortgather block size (8 waves)
constexpr int NBMAX    = 512;    // max node buckets (n <= 131072)
constexpr int MAXBLK   = 1024;   // max partition blocks (E <= 2M)

__device__ __forceinline__ unsigned int f2bf(float f) {
    unsigned int u = __float_as_uint(f);
    return (u + 0x7FFFu + ((u >> 16) & 1u)) >> 16;   // RNE to bf16
}
__device__ __forceinline__ float bf2f_lo(unsigned int v) { return __uint_as_float(v << 16); }
__device__ __forceinline__ float bf2f_hi(unsigned int v) { return __uint_as_float(v & 0xFFFF0000u); }

// ---------------- main path ----------------

// Each block owns edges [blk*EPB, blk*EPB+cnt) and its own output region.
// Writes: recB[blk][i] (u32, sorted by dst-bucket), srecB[blk][i] (u8, sorted
// by src-bucket), tabD/tabS[blk][0..NB] = exclusive scan (u16). All streaming.
__global__ __launch_bounds__(PTHREADS)
void partition_kernel(const int* __restrict__ src, const int* __restrict__ dst,
                      unsigned int* __restrict__ recB, unsigned char* __restrict__ srecB,
                      unsigned short* __restrict__ tabD, unsigned short* __restrict__ tabS,
                      int E, int NB, int NBP) {
    __shared__ unsigned int  srt[EPB];      // 8 KB sorted dst-records
    __shared__ unsigned char ssrt[EPB];     // 2 KB sorted src bytes
    __shared__ unsigned int histDS[NBMAX];  // low16 = D count, high16 = S count; reused as rank
    __shared__ unsigned int rsDS[NBMAX];    // packed exclusive scans
    __shared__ unsigned int wsums[PTHREADS / 64];
    __shared__ unsigned int carry;

    const int blk  = blockIdx.x;
    const int base = blk * EPB;
    const int tid  = threadIdx.x;
    const int lane = tid & 63;
    const int wid  = tid >> 6;
    const int cnt  = min(EPB, E - base);
    const bool full = (cnt == EPB);

    for (int b = tid; b < NB; b += PTHREADS) histDS[b] = 0;
    __syncthreads();

    // ---- pass 1: count per bucket (packed) ----
    if (full) {
        const int4* s4 = (const int4*)(src + base);
        const int4* d4 = (const int4*)(dst + base);
        #pragma unroll
        for (int k = 0; k < EPT / 4; ++k) {
            int4 sv = s4[tid + k * PTHREADS];
            int4 dv = d4[tid + k * PTHREADS];
            atomicAdd(&histDS[dv.x >> 8], 1u); atomicAdd(&histDS[sv.x >> 8], 0x10000u);
            atomicAdd(&histDS[dv.y >> 8], 1u); atomicAdd(&histDS[sv.y >> 8], 0x10000u);
            atomicAdd(&histDS[dv.z >> 8], 1u); atomicAdd(&histDS[sv.z >> 8], 0x10000u);
            atomicAdd(&histDS[dv.w >> 8], 1u); atomicAdd(&histDS[sv.w >> 8], 0x10000u);
        }
    } else {
        for (int k = 0; k < EPT; ++k) {
            int e = tid + k * PTHREADS;
            if (e < cnt) {
                atomicAdd(&histDS[dst[base + e] >> 8], 1u);
                atomicAdd(&histDS[src[base + e] >> 8], 0x10000u);
            }
        }
    }
    __syncthreads();

    // ---- packed exclusive scan histDS -> rsDS (halves scan independently) ----
    if (tid == 0) carry = 0;
    __syncthreads();
    for (int bp = 0; bp < NB; bp += PTHREADS) {
        int idx = bp + tid;
        unsigned int orig = (idx < NB) ? histDS[idx] : 0u;
        if (idx < NB) histDS[idx] = 0;
        unsigned int v = orig;
        #pragma unroll
        for (int off = 1; off < 64; off <<= 1) {
            unsigned int t = __shfl_up(v, off);
            if (lane >= off) v += t;
        }
        if (lane == 63) wsums[wid] = v;
        __syncthreads();
        unsigned int add = carry;
        for (int w = 0; w < wid; ++w) add += wsums[w];
        if (idx < NB) rsDS[idx] = v - orig + add;
        __syncthreads();
        if (tid == 0) {
            unsigned int s = carry;
            for (int w = 0; w < PTHREADS / 64; ++w) s += wsums[w];
            carry = s;
        }
        __syncthreads();
    }

    // ---- write prefix tables (coalesced u16) ----
    for (int b = tid; b <= NB; b += PTHREADS) {
        unsigned int v = (b < NB) ? rsDS[b] : ((unsigned int)cnt | ((unsigned int)cnt << 16));
        tabD[(size_t)blk * NBP + b] = (unsigned short)(v & 0xFFFFu);
        tabS[(size_t)blk * NBP + b] = (unsigned short)(v >> 16);
    }

    // ---- pass 2: place into LDS sorted position ----
    if (full) {
        const int4* s4 = (const int4*)(src + base);
        const int4* d4 = (const int4*)(dst + base);
        #pragma unroll
        for (int k = 0; k < EPT / 4; ++k) {
            int4 sv = s4[tid + k * PTHREADS];
            int4 dv = d4[tid + k * PTHREADS];
            int ss[4] = {sv.x, sv.y, sv.z, sv.w};
            int tt[4] = {dv.x, dv.y, dv.z, dv.w};
            #pragma unroll
            for (int j = 0; j < 4; ++j) {
                int s = ss[j], t = tt[j];
                int bD = t >> 8;
                unsigned int r = atomicAdd(&histDS[bD], 1u) & 0xFFFFu;
                srt[(rsDS[bD] & 0xFFFFu) + r] = ((unsigned int)s << 8) | (unsigned int)(t & (BKT - 1));
                int bS = s >> 8;
                unsigned int r2 = atomicAdd(&histDS[bS], 0x10000u) >> 16;
                ssrt[(rsDS[bS] >> 16) + r2] = (unsigned char)(s & (BKT - 1));
            }
        }
    } else {
        for (int k = 0; k < EPT; ++k) {
            int e = tid + k * PTHREADS;
            if (e < cnt) {
                int s = src[base + e], t = dst[base + e];
                int bD = t >> 8;
                unsigned int r = atomicAdd(&histDS[bD], 1u) & 0xFFFFu;
                srt[(rsDS[bD] & 0xFFFFu) + r] = ((unsigned int)s << 8) | (unsigned int)(t & (BKT - 1));
                int bS = s >> 8;
                unsigned int r2 = atomicAdd(&histDS[bS], 0x10000u) >> 16;
                ssrt[(rsDS[bS] >> 16) + r2] = (unsigned char)(s & (BKT - 1));
            }
        }
    }
    __syncthreads();

    // ---- pass 3: stream full region out (bytes beyond cnt are never read) ----
    {
        uint4* go = (uint4*)(recB + (size_t)blk * EPB);
        const uint4* gi = (const uint4*)srt;
        for (int i = tid; i < EPB / 4; i += PTHREADS) go[i] = gi[i];
        uint4* so = (uint4*)(srecB + (size_t)blk * EPB);
        const uint4* si = (const uint4*)ssrt;
        for (int i = tid; i < EPB / 16; i += PTHREADS) so[i] = si[i];
    }
}

// Per-bucket out-degree histogram from srecB segments -> norm[]. Latency-bound
// scattered byte reads only; the streaming x->yh pass is a separate kernel.
__global__ __launch_bounds__(256)
void degnorm_kernel(const unsigned char* __restrict__ srecB, const unsigned short* __restrict__ tabS,
                    float* __restrict__ norm, int n, int NBLK, int NBP) {
    const int b   = blockIdx.x;
    const int tid = threadIdx.x;
    __shared__ unsigned int segO[MAXBLK];      // o0 | o1<<16 (offsets < 2048)
    __shared__ int hist[BKT];
    hist[tid] = 0;                             // BKT == blockDim == 256
    for (int blk = tid; blk < NBLK; blk += 256) {
        unsigned int o0 = tabS[(size_t)blk * NBP + b];
        unsigned int o1 = tabS[(size_t)blk * NBP + b + 1];
        segO[blk] = o0 | (o1 << 16);
    }
    __syncthreads();
    const int g  = tid >> 3;                   // 32 groups of 8 lanes
    const int gl = tid & 7;
    for (int blk = g; blk < NBLK; blk += 32) {
        unsigned int u = segO[blk];
        int o0 = (int)(u & 0xFFFFu), o1 = (int)(u >> 16);
        const unsigned char* p = srecB + (size_t)blk * EPB;
        for (int j = o0 + gl; j < o1; j += 8) atomicAdd(&hist[p[j]], 1);
    }
    __syncthreads();
    int node = b * BKT + tid;
    if (node < n) norm[node] = rsqrtf(fmaxf((float)hist[tid], 1.0f));
}

// Pure streaming: yh = bf16(norm * x). Grid-strided, full HBM bandwidth.
__global__ __launch_bounds__(256)
void yhconv_kernel(const float2* __restrict__ x2, const float* __restrict__ norm,
                   unsigned int* __restrict__ yh, int total) {
    int stride = gridDim.x * 256;
    for (int i = blockIdx.x * 256 + threadIdx.x; i < total; i += stride) {
        float2 v = x2[i];
        float nm = norm[i >> 5];               // 32 float2 per node; broadcast load
        yh[i] = f2bf(v.x * nm) | (f2bf(v.y * nm) << 16);
    }
}

// One block per bucket (512 threads = 8 waves, ~38 KB LDS -> 4 blocks/CU).
// Copy bucket b's records from per-block segments into LDS (8-lane groups),
// counting-sort to per-node src lists, then gather yh rows (8 nodes/wave,
// 8-deep unroll). Chunked if cnt > CAPB (rare).
__global__ __launch_bounds__(GTHREADS)
void sortgather_kernel(const unsigned int* __restrict__ recB, const unsigned short* __restrict__ tabD,
                       const float* __restrict__ norm, const uint4* __restrict__ yr4,
                       const float4* __restrict__ x4, float4* __restrict__ out4,
                       int n, int NBLK, int NBP) {
    __shared__ unsigned int recs[CAPB];        // 14 KB
    __shared__ unsigned int srcs[CAPB];        // 14 KB
    __shared__ unsigned short segoff[MAXBLK];  // 2 KB
    __shared__ unsigned int dstoff[MAXBLK + 1];// 4 KB (len -> exclusive scan)
    __shared__ int hist[BKT];                  // 1 KB
    __shared__ int rankb[BKT];                 // 1 KB
    __shared__ int rsL[BKT];                   // 1 KB
    __shared__ float nrmL[BKT];                // 1 KB
    __shared__ unsigned int wsums[GTHREADS / 64];
    __shared__ unsigned int carry;
    const int b    = blockIdx.x;
    const int tid  = threadIdx.x;
    const int lane = tid & 63;
    const int wid  = tid >> 6;

    // segment table for this bucket
    for (int blk = tid; blk < NBLK; blk += GTHREADS) {
        unsigned int o0 = tabD[(size_t)blk * NBP + b];
        unsigned int o1 = tabD[(size_t)blk * NBP + b + 1];
        segoff[blk] = (unsigned short)o0;
        dstoff[blk] = o1 - o0;                 // length; scanned in place below
    }
    if (tid < BKT) {
        int node = b * BKT + tid;
        nrmL[tid] = (node < n) ? norm[node] : 1.0f;
    }
    if (tid == 0) carry = 0;
    __syncthreads();
    // in-place exclusive scan of dstoff[0..NBLK)
    for (int bp = 0; bp < NBLK; bp += GTHREADS) {
        int idx = bp + tid;
        unsigned int orig = (idx < NBLK) ? dstoff[idx] : 0u;
        unsigned int v = orig;
        #pragma unroll
        for (int off = 1; off < 64; off <<= 1) {
            unsigned int t = __shfl_up(v, off);
            if (lane >= off) v += t;
        }
        if (lane == 63) wsums[wid] = v;
        __syncthreads();
        unsigned int add = carry;
        for (int w = 0; w < wid; ++w) add += wsums[w];
        if (idx < NBLK) dstoff[idx] = v - orig + add;
        __syncthreads();
        if (tid == 0) {
            unsigned int s = carry;
            for (int w = 0; w < GTHREADS / 64; ++w) s += wsums[w];
            carry = s;
        }
        __syncthreads();
    }
    if (tid == 0) dstoff[NBLK] = carry;
    __syncthreads();
    const int cnt = (int)dstoff[NBLK];
    const int nch = (cnt > CAPB) ? (cnt + CAPB - 1) / CAPB : 1;

    const int fl  = lane & 7;                  // uint4 index within 128B row
    const int oct = lane >> 3;                 // node within 8-node group

    for (int c = 0; c < nch; ++c) {
        const unsigned int lo = (unsigned int)c * CAPB;
        const unsigned int hi = min((unsigned int)cnt, lo + (unsigned int)CAPB);
        const int wlen = (int)(hi - lo);
        // copy window [lo,hi) into recs; 8-lane groups per segment (avg ~5
        // records/segment at EPB=2048 -> 64 groups, balanced)
        {
            const int cg  = tid >> 3;
            const int cgl = tid & 7;
            for (int blk = cg; blk < NBLK; blk += GTHREADS / 8) {
                unsigned int dbase = dstoff[blk], dend = dstoff[blk + 1];
                unsigned int s0 = max(dbase, lo), s1 = min(dend, hi);
                if (s0 < s1) {
                    size_t glo = (size_t)blk * EPB + segoff[blk] + (s0 - dbase);
                    for (unsigned int j = cgl; j < s1 - s0; j += 8)
                        recs[s0 - lo + j] = recB[glo + j];
                }
            }
        }
        __syncthreads();                        // prev gather done + copy done
        if (tid < BKT) hist[tid] = 0;
        __syncthreads();
        for (int i = tid; i < wlen; i += GTHREADS) atomicAdd(&hist[recs[i] & (BKT - 1)], 1);
        __syncthreads();
        // scan hist[0..BKT) (threads < 256 = 4 waves)
        {
            int v = (tid < BKT) ? hist[tid] : 0;
            #pragma unroll
            for (int off = 1; off < 64; off <<= 1) {
                int t = __shfl_up(v, off);
                if (lane >= off) v += t;
            }
            if (tid < BKT && lane == 63) wsums[wid] = (unsigned int)v;
            __syncthreads();
            if (tid < BKT) {
                int add = 0;
                for (int w = 0; w < wid; ++w) add += (int)wsums[w];
                int excl = v + add - hist[tid];
                rankb[tid] = excl;
                rsL[tid]   = excl;
            }
        }
        __syncthreads();
        for (int i = tid; i < wlen; i += GTHREADS) {
            unsigned int v = recs[i];
            int pos = atomicAdd(&rankb[v & (BKT - 1)], 1);
            srcs[pos] = v >> 8;
        }
        __syncthreads();

        // ---- gather: 8 waves x 8 nodes -> 64 nodes/round, 4 rounds ----
        #pragma unroll
        for (int r = 0; r < BKT / 64; ++r) {
            int ln   = r * 64 + wid * 8 + oct;
            int node = b * BKT + ln;
            bool valid = node < n;
            int rsl = valid ? rsL[ln]  : 0;
            int cl  = valid ? hist[ln] : 0;
            int m = cl;                        // uniform loop count = wave-max
            m = max(m, __shfl_xor(m, 8));
            m = max(m, __shfl_xor(m, 16));
            m = max(m, __shfl_xor(m, 32));
            float a0 = 0.f, a1 = 0.f, a2 = 0.f, a3 = 0.f;
            float a4 = 0.f, a5 = 0.f, a6 = 0.f, a7 = 0.f;
            for (int k = 0; k < m; k += 8) {
                int sb[8];
                #pragma unroll
                for (int j = 0; j < 8; ++j) {  // 8 LDS reads issue together
                    int kj = k + j;
                    sb[j] = (kj < cl) ? (int)srcs[rsl + kj] : -1;
                }
                #pragma unroll
                for (int j = 0; j < 8; ++j) {  // 8 row loads in flight
                    bool take = sb[j] >= 0;
                    int s = take ? sb[j] : 0;  // dummy hits node 0's cached row
                    uint4 v = yr4[(size_t)s * 8 + fl];
                    if (!take) { v.x = 0u; v.y = 0u; v.z = 0u; v.w = 0u; }
                    a0 += bf2f_lo(v.x); a1 += bf2f_hi(v.x);
                    a2 += bf2f_lo(v.y); a3 += bf2f_hi(v.y);
                    a4 += bf2f_lo(v.z); a5 += bf2f_hi(v.z);
                    a6 += bf2f_lo(v.w); a7 += bf2f_hi(v.w);
                }
            }
            if (valid) {
                float nt = nrmL[ln];
                size_t basei = (size_t)node * 16 + fl * 2;
                float4 r0, r1;
                if (c == 0) {
                    float4 xv0 = x4[basei], xv1 = x4[basei + 1];
                    r0.x = a0 * nt + EPS * xv0.x;  r0.y = a1 * nt + EPS * xv0.y;
                    r0.z = a2 * nt + EPS * xv0.z;  r0.w = a3 * nt + EPS * xv0.w;
                    r1.x = a4 * nt + EPS * xv1.x;  r1.y = a5 * nt + EPS * xv1.y;
                    r1.z = a6 * nt + EPS * xv1.z;  r1.w = a7 * nt + EPS * xv1.w;
                } else {                       // rare multi-chunk path: RMW
                    float4 p0 = out4[basei], p1 = out4[basei + 1];
                    r0.x = p0.x + a0 * nt;  r0.y = p0.y + a1 * nt;
                    r0.z = p0.z + a2 * nt;  r0.w = p0.w + a3 * nt;
                    r1.x = p1.x + a4 * nt;  r1.y = p1.y + a5 * nt;
                    r1.z = p1.z + a6 * nt;  r1.w = p1.w + a7 * nt;
                }
                out4[basei] = r0;              // coalesced: 32B/lane
                out4[basei + 1] = r1;
            }
        }
    }
}

// ---------------- tiny-ws / big-n fallback (round-1 proven) ----------------

__global__ void fb_hist(const int* __restrict__ src, int* __restrict__ deg, int E) {
    int e = blockIdx.x * blockDim.x + threadIdx.x;
    if (e < E) atomicAdd(&deg[src[e]], 1);
}
__global__ void fb_norm(const int* __restrict__ deg, float* __restrict__ norm, int n) {
    int i = blockIdx.x * blockDim.x + threadIdx.x;
    if (i < n) norm[i] = rsqrtf(fmaxf((float)deg[i], 1.0f));
}
__global__ void fb_init_out(const float4* __restrict__ x, float4* __restrict__ out, int n4) {
    int i = blockIdx.x * blockDim.x + threadIdx.x;
    if (i < n4) {
        float4 v = x[i];
        out[i] = make_float4(v.x * EPS, v.y * EPS, v.z * EPS, v.w * EPS);
    }
}
__global__ void fb_scatter(const float* __restrict__ x, const int* __restrict__ src,
                           const int* __restrict__ dst, const float* __restrict__ norm,
                           float* __restrict__ out, int E) {
    long long tid = (long long)blockIdx.x * blockDim.x + threadIdx.x;
    int e = (int)(tid >> 6), d = (int)(tid & 63);
    if (e < E) {
        int s = src[e], t = dst[e];
        atomicAdd(&out[(size_t)t * D + d], norm[s] * norm[t] * x[(size_t)s * D + d]);
    }
}

// ---------------- launcher ----------------

extern "C" void kernel_launch(void* const* d_in, const int* in_sizes, int n_in,
                              void* d_out, int out_size, void* d_ws, size_t ws_size,
                              hipStream_t stream) {
    const float* x   = (const float*)d_in[0];
    const int*   src = (const int*)d_in[1];
    const int*   dst = (const int*)d_in[2];
    float* out = (float*)d_out;

    const int ND = in_sizes[0];
    const int E  = in_sizes[1];
    const int n  = ND / D;
    const int NB   = (n + BKT - 1) / BKT;
    const int NBLK = (E + EPB - 1) / EPB;
    const int NBP  = NB + 1;
    constexpr int B = 256;

    // workspace layout (16B-aligned chunks)
    size_t off = 0;
    auto take = [&](size_t bytes) { size_t o = off; off = (off + bytes + 15) & ~15ull; return o; };
    size_t o_rec  = take((size_t)NBLK * EPB * 4);       // recB u32
    size_t o_srec = take((size_t)NBLK * EPB);           // srecB u8
    size_t o_tabD = take((size_t)NBLK * NBP * 2);       // tabD u16
    size_t o_tabS = take((size_t)NBLK * NBP * 2);       // tabS u16
    size_t o_yh   = take((size_t)ND * 2);               // yh u32 (bf16x2)
    size_t o_norm = take((size_t)n * 4);                // norm f32
    size_t need = off;

    if (NB <= NBMAX && NBLK <= MAXBLK && n < (1 << 24) && need <= ws_size && E > 0) {
        char* ws = (char*)d_ws;
        unsigned int*   recB  = (unsigned int*)(ws + o_rec);
        unsigned char*  srecB = (unsigned char*)(ws + o_srec);
        unsigned short* tabD  = (unsigned short*)(ws + o_tabD);
        unsigned short* tabS  = (unsigned short*)(ws + o_tabS);
        unsigned int*   yh    = (unsigned int*)(ws + o_yh);
        float*          norm  = (float*)(ws + o_norm);

        partition_kernel<<<NBLK, PTHREADS, 0, stream>>>(src, dst, recB, srecB,
                                                        tabD, tabS, E, NB, NBP);
        degnorm_kernel<<<NB, 256, 0, stream>>>(srecB, tabS, norm, n, NBLK, NBP);
        int yt = ND / 2;
        int yg = (yt + 255) / 256; if (yg > 2048) yg = 2048;
        yhconv_kernel<<<yg, 256, 0, stream>>>((const float2*)x, norm, yh, yt);
        sortgather_kernel<<<NB, GTHREADS, 0, stream>>>(recB, tabD, norm, (const uint4*)yh,
                                                       (const float4*)x, (float4*)out,
                                                       n, NBLK, NBP);
    } else {
        int*   deg  = (int*)d_ws;
        float* norm = (float*)d_ws + n;
        hipMemsetAsync(deg, 0, (size_t)n * sizeof(int), stream);
        fb_hist<<<(E + B - 1) / B, B, 0, stream>>>(src, deg, E);
        fb_norm<<<(n + B - 1) / B, B, 0, stream>>>(deg, norm, n);
        fb_init_out<<<(ND / 4 + B - 1) / B, B, 0, stream>>>((const float4*)x, (float4*)out, ND / 4);
        long long total = (long long)E * D;
        fb_scatter<<<(int)((total + B - 1) / B), B, 0, stream>>>(x, src, dst, norm, out, E);
    }
}

// Round 10
// 165.044 us; speedup vs baseline: 1.0293x; 1.0091x over previous
//
#include <hip/hip_runtime.h>

// GCN aggregation: out[t] = norm[t] * sum_{e:dst=t} norm[src]*x[src] + EPS*x[t]
// Round 19 = round 18 resubmitted (round-18 bench died in container acquisition,
// not in the kernel: no compile error, no counters; LDS 39.3 KB, guarded WS).
// Thesis: sortgather occupancy is GRID-limited (NB=391 blocks ~1.5/CU) ->
// resident waves = grid x waves/block. 512 thr measured 27% occ / 65 us;
// 1024 thr (16 waves, ~40 KB LDS) raises ceiling to 76%; round-4's 1024-thr
// variant ran <44 us. Prior 1024-thr failure modes fixed: 16-lane segment-copy
// groups (r5 used 64-lane), single block per bucket (r7 duplicated prologue).
// EPB=4096 halves segment count for degnorm/sortgather prologues; degnorm 512
// thr. 4 launches, no memset.
constexpr int D        = 64;
constexpr float EPS    = 0.5f;
constexpr int BKT      = 256;    // nodes per bucket
constexpr int CAPB     = 4096;   // sortgather LDS chunk capacity (records)
constexpr int EPB      = 4096;   // edges per partition block (= region stride)
constexpr int PTHREADS = 512;
constexpr int EPT      = EPB / PTHREADS;   // 8
constexpr int GTHREADS = 1024;   // sortgather block size (16 waves)
constexpr int NTHREADS = 512;    // degnorm block size
constexpr int NBMAX    = 512;    // max node buckets (n <= 131072)
constexpr int MAXBLK   = 512;    // max partition blocks (E <= 2M)

__device__ __forceinline__ unsigned int f2bf(float f) {
    unsigned int u = __float_as_uint(f);
    return (u + 0x7FFFu + ((u >> 16) & 1u)) >> 16;   // RNE to bf16
}
__device__ __forceinline__ float bf2f_lo(unsigned int v) { return __uint_as_float(v << 16); }
__device__ __forceinline__ float bf2f_hi(unsigned int v) { return __uint_as_float(v & 0xFFFF0000u); }

// ---------------- main path ----------------

// Each block owns edges [blk*EPB, blk*EPB+cnt) and its own output region.
// Writes: recB[blk][i] (u32, sorted by dst-bucket), srecB[blk][i] (u8, sorted
// by src-bucket), tabD/tabS[blk][0..NB] = exclusive scan (u16). All streaming.
__global__ __launch_bounds__(PTHREADS)
void partition_kernel(const int* __restrict__ src, const int* __restrict__ dst,
                      unsigned int* __restrict__ recB, unsigned char* __restrict__ srecB,
                      unsigned short* __restrict__ tabD, unsigned short* __restrict__ tabS,
                      int E, int NB, int NBP) {
    __shared__ unsigned int  srt[EPB];      // 16 KB sorted dst-records
    __shared__ unsigned char ssrt[EPB];     // 4 KB sorted src bytes
    __shared__ unsigned int histDS[NBMAX];  // low16 = D count, high16 = S count; reused as rank
    __shared__ unsigned int rsDS[NBMAX];    // packed exclusive scans
    __shared__ unsigned int wsums[PTHREADS / 64];
    __shared__ unsigned int carry;

    const int blk  = blockIdx.x;
    const int base = blk * EPB;
    const int tid  = threadIdx.x;
    const int lane = tid & 63;
    const int wid  = tid >> 6;
    const int cnt  = min(EPB, E - base);
    const bool full = (cnt == EPB);

    for (int b = tid; b < NB; b += PTHREADS) histDS[b] = 0;
    __syncthreads();

    // ---- pass 1: count per bucket (packed) ----
    if (full) {
        const int4* s4 = (const int4*)(src + base);
        const int4* d4 = (const int4*)(dst + base);
        #pragma unroll
        for (int k = 0; k < EPT / 4; ++k) {
            int4 sv = s4[tid + k * PTHREADS];
            int4 dv = d4[tid + k * PTHREADS];
            atomicAdd(&histDS[dv.x >> 8], 1u); atomicAdd(&histDS[sv.x >> 8], 0x10000u);
            atomicAdd(&histDS[dv.y >> 8], 1u); atomicAdd(&histDS[sv.y >> 8], 0x10000u);
            atomicAdd(&histDS[dv.z >> 8], 1u); atomicAdd(&histDS[sv.z >> 8], 0x10000u);
            atomicAdd(&histDS[dv.w >> 8], 1u); atomicAdd(&histDS[sv.w >> 8], 0x10000u);
        }
    } else {
        for (int k = 0; k < EPT; ++k) {
            int e = tid + k * PTHREADS;
            if (e < cnt) {
                atomicAdd(&histDS[dst[base + e] >> 8], 1u);
                atomicAdd(&histDS[src[base + e] >> 8], 0x10000u);
            }
        }
    }
    __syncthreads();

    // ---- packed exclusive scan histDS -> rsDS (halves scan independently) ----
    if (tid == 0) carry = 0;
    __syncthreads();
    for (int bp = 0; bp < NB; bp += PTHREADS) {
        int idx = bp + tid;
        unsigned int orig = (idx < NB) ? histDS[idx] : 0u;
        if (idx < NB) histDS[idx] = 0;
        unsigned int v = orig;
        #pragma unroll
        for (int off = 1; off < 64; off <<= 1) {
            unsigned int t = __shfl_up(v, off);
            if (lane >= off) v += t;
        }
        if (lane == 63) wsums[wid] = v;
        __syncthreads();
        unsigned int add = carry;
        for (int w = 0; w < wid; ++w) add += wsums[w];
        if (idx < NB) rsDS[idx] = v - orig + add;
        __syncthreads();
        if (tid == 0) {
            unsigned int s = carry;
            for (int w = 0; w < PTHREADS / 64; ++w) s += wsums[w];
            carry = s;
        }
        __syncthreads();
    }

    // ---- write prefix tables (coalesced u16) ----
    for (int b = tid; b <= NB; b += PTHREADS) {
        unsigned int v = (b < NB) ? rsDS[b] : ((unsigned int)cnt | ((unsigned int)cnt << 16));
        tabD[(size_t)blk * NBP + b] = (unsigned short)(v & 0xFFFFu);
        tabS[(size_t)blk * NBP + b] = (unsigned short)(v >> 16);
    }

    // ---- pass 2: place into LDS sorted position ----
    if (full) {
        const int4* s4 = (const int4*)(src + base);
        const int4* d4 = (const int4*)(dst + base);
        #pragma unroll
        for (int k = 0; k < EPT / 4; ++k) {
            int4 sv = s4[tid + k * PTHREADS];
            int4 dv = d4[tid + k * PTHREADS];
            int ss[4] = {sv.x, sv.y, sv.z, sv.w};
            int tt[4] = {dv.x, dv.y, dv.z, dv.w};
            #pragma unroll
            for (int j = 0; j < 4; ++j) {
                int s = ss[j], t = tt[j];
                int bD = t >> 8;
                unsigned int r = atomicAdd(&histDS[bD], 1u) & 0xFFFFu;
                srt[(rsDS[bD] & 0xFFFFu) + r] = ((unsigned int)s << 8) | (unsigned int)(t & (BKT - 1));
                int bS = s >> 8;
                unsigned int r2 = atomicAdd(&histDS[bS], 0x10000u) >> 16;
                ssrt[(rsDS[bS] >> 16) + r2] = (unsigned char)(s & (BKT - 1));
            }
        }
    } else {
        for (int k = 0; k < EPT; ++k) {
            int e = tid + k * PTHREADS;
            if (e < cnt) {
                int s = src[base + e], t = dst[base + e];
                int bD = t >> 8;
                unsigned int r = atomicAdd(&histDS[bD], 1u) & 0xFFFFu;
                srt[(rsDS[bD] & 0xFFFFu) + r] = ((unsigned int)s << 8) | (unsigned int)(t & (BKT - 1));
                int bS = s >> 8;
                unsigned int r2 = atomicAdd(&histDS[bS], 0x10000u) >> 16;
                ssrt[(rsDS[bS] >> 16) + r2] = (unsigned char)(s & (BKT - 1));
            }
        }
    }
    __syncthreads();

    // ---- pass 3: stream full region out (bytes beyond cnt are never read) ----
    {
        uint4* go = (uint4*)(recB + (size_t)blk * EPB);
        const uint4* gi = (const uint4*)srt;
        for (int i = tid; i < EPB / 4; i += PTHREADS) go[i] = gi[i];
        uint4* so = (uint4*)(srecB + (size_t)blk * EPB);
        const uint4* si = (const uint4*)ssrt;
        for (int i = tid; i < EPB / 16; i += PTHREADS) so[i] = si[i];
    }
}

// Per-bucket out-degree histogram from srecB segments -> norm[]. 512 threads
// (grid-limited at NB blocks -> more waves/block). 16-lane groups per segment.
__global__ __launch_bounds__(NTHREADS)
void degnorm_kernel(const unsigned char* __restrict__ srecB, const unsigned short* __restrict__ tabS,
                    float* __restrict__ norm, int n, int NBLK, int NBP) {
    const int b   = blockIdx.x;
    const int tid = threadIdx.x;
    __shared__ unsigned int segO[MAXBLK];      // o0 | o1<<16 (offsets <= 4096)
    __shared__ int hist[BKT];
    if (tid < BKT) hist[tid] = 0;
    for (int blk = tid; blk < NBLK; blk += NTHREADS) {
        unsigned int o0 = tabS[(size_t)blk * NBP + b];
        unsigned int o1 = tabS[(size_t)blk * NBP + b + 1];
        segO[blk] = o0 | (o1 << 16);
    }
    __syncthreads();
    const int g  = tid >> 4;                   // 32 groups of 16 lanes
    const int gl = tid & 15;
    for (int blk = g; blk < NBLK; blk += NTHREADS / 16) {
        unsigned int u = segO[blk];
        int o0 = (int)(u & 0xFFFFu), o1 = (int)(u >> 16);
        const unsigned char* p = srecB + (size_t)blk * EPB;
        for (int j = o0 + gl; j < o1; j += 16) atomicAdd(&hist[p[j]], 1);
    }
    __syncthreads();
    if (tid < BKT) {
        int node = b * BKT + tid;
        if (node < n) norm[node] = rsqrtf(fmaxf((float)hist[tid], 1.0f));
    }
}

// Pure streaming: yh = bf16(norm * x). Grid-strided, full HBM bandwidth.
__global__ __launch_bounds__(256)
void yhconv_kernel(const float2* __restrict__ x2, const float* __restrict__ norm,
                   unsigned int* __restrict__ yh, int total) {
    int stride = gridDim.x * 256;
    for (int i = blockIdx.x * 256 + threadIdx.x; i < total; i += stride) {
        float2 v = x2[i];
        float nm = norm[i >> 5];               // 32 float2 per node; broadcast load
        yh[i] = f2bf(v.x * nm) | (f2bf(v.y * nm) << 16);
    }
}

// One block per bucket, 1024 threads = 16 waves (~40 KB LDS). Grid is only NB
// blocks (~1.5/CU) so occupancy = grid x waves/block: 16 waves -> 76% ceiling
// (vs 38% at 512 thr, r6-r8 measured 27%). Copy bucket b's records from
// per-block segments into LDS (16-lane groups), counting-sort to per-node src
// lists, then gather yh rows (8 nodes/wave, 8-deep unroll). Chunked if
// cnt > CAPB (rare).
__global__ __launch_bounds__(GTHREADS)
void sortgather_kernel(const unsigned int* __restrict__ recB, const unsigned short* __restrict__ tabD,
                       const float* __restrict__ norm, const uint4* __restrict__ yr4,
                       const float4* __restrict__ x4, float4* __restrict__ out4,
                       int n, int NBLK, int NBP) {
    __shared__ unsigned int recs[CAPB];        // 16 KB
    __shared__ unsigned int srcs[CAPB];        // 16 KB
    __shared__ unsigned short segoff[MAXBLK];  // 1 KB
    __shared__ unsigned int dstoff[MAXBLK + 1];// 2 KB (len -> exclusive scan)
    __shared__ int hist[BKT];                  // 1 KB
    __shared__ int rankb[BKT];                 // 1 KB
    __shared__ int rsL[BKT];                   // 1 KB
    __shared__ float nrmL[BKT];                // 1 KB
    __shared__ unsigned int wsums[GTHREADS / 64];
    __shared__ unsigned int carry;
    const int b    = blockIdx.x;
    const int tid  = threadIdx.x;
    const int lane = tid & 63;
    const int wid  = tid >> 6;

    // segment table for this bucket
    for (int blk = tid; blk < NBLK; blk += GTHREADS) {
        unsigned int o0 = tabD[(size_t)blk * NBP + b];
        unsigned int o1 = tabD[(size_t)blk * NBP + b + 1];
        segoff[blk] = (unsigned short)o0;
        dstoff[blk] = o1 - o0;                 // length; scanned in place below
    }
    if (tid < BKT) {
        int node = b * BKT + tid;
        nrmL[tid] = (node < n) ? norm[node] : 1.0f;
    }
    if (tid == 0) carry = 0;
    __syncthreads();
    // in-place exclusive scan of dstoff[0..NBLK)
    for (int bp = 0; bp < NBLK; bp += GTHREADS) {
        int idx = bp + tid;
        unsigned int orig = (idx < NBLK) ? dstoff[idx] : 0u;
        unsigned int v = orig;
        #pragma unroll
        for (int off = 1; off < 64; off <<= 1) {
            unsigned int t = __shfl_up(v, off);
            if (lane >= off) v += t;
        }
        if (lane == 63) wsums[wid] = v;
        __syncthreads();
        unsigned int add = carry;
        for (int w = 0; w < wid; ++w) add += wsums[w];
        if (idx < NBLK) dstoff[idx] = v - orig + add;
        __syncthreads();
        if (tid == 0) {
            unsigned int s = carry;
            for (int w = 0; w < GTHREADS / 64; ++w) s += wsums[w];
            carry = s;
        }
        __syncthreads();
    }
    if (tid == 0) dstoff[NBLK] = carry;
    __syncthreads();
    const int cnt = (int)dstoff[NBLK];
    const int nch = (cnt > CAPB) ? (cnt + CAPB - 1) / CAPB : 1;

    const int fl  = lane & 7;                  // uint4 index within 128B row
    const int oct = lane >> 3;                 // node within 8-node group

    for (int c = 0; c < nch; ++c) {
        const unsigned int lo = (unsigned int)c * CAPB;
        const unsigned int hi = min((unsigned int)cnt, lo + (unsigned int)CAPB);
        const int wlen = (int)(hi - lo);
        // copy window [lo,hi) into recs; 16-lane groups per segment (avg ~10
        // records/segment at EPB=4096 -> 64 groups, balanced)
        {
            const int cg  = tid >> 4;
            const int cgl = tid & 15;
            for (int blk = cg; blk < NBLK; blk += GTHREADS / 16) {
                unsigned int dbase = dstoff[blk], dend = dstoff[blk + 1];
                unsigned int s0 = max(dbase, lo), s1 = min(dend, hi);
                if (s0 < s1) {
                    size_t glo = (size_t)blk * EPB + segoff[blk] + (s0 - dbase);
                    for (unsigned int j = cgl; j < s1 - s0; j += 16)
                        recs[s0 - lo + j] = recB[glo + j];
                }
            }
        }
        __syncthreads();                        // prev gather done + copy done
        if (tid < BKT) hist[tid] = 0;
        __syncthreads();
        for (int i = tid; i < wlen; i += GTHREADS) atomicAdd(&hist[recs[i] & (BKT - 1)], 1);
        __syncthreads();
        // scan hist[0..BKT) (threads < 256 = 4 waves)
        {
            int v = (tid < BKT) ? hist[tid] : 0;
            #pragma unroll
            for (int off = 1; off < 64; off <<= 1) {
                int t = __shfl_up(v, off);
                if (lane >= off) v += t;
            }
            if (tid < BKT && lane == 63) wsums[wid] = (unsigned int)v;
            __syncthreads();
            if (tid < BKT) {
                int add = 0;
                for (int w = 0; w < wid; ++w) add += (int)wsums[w];
                int excl = v + add - hist[tid];
                rankb[tid] = excl;
                rsL[tid]   = excl;
            }
        }
        __syncthreads();
        for (int i = tid; i < wlen; i += GTHREADS) {
            unsigned int v = recs[i];
            int pos = atomicAdd(&rankb[v & (BKT - 1)], 1);
            srcs[pos] = v >> 8;
        }
        __syncthreads();

        // ---- gather: 16 waves x 8 nodes -> 128 nodes/round, 2 rounds ----
        #pragma unroll
        for (int r = 0; r < BKT / 128; ++r) {
            int ln   = r * 128 + wid * 8 + oct;
            int node = b * BKT + ln;
            bool valid = node < n;
            int rsl = valid ? rsL[ln]  : 0;
            int cl  = valid ? hist[ln] : 0;
            int m = cl;                        // uniform loop count = wave-max
            m = max(m, __shfl_xor(m, 8));
            m = max(m, __shfl_xor(m, 16));
            m = max(m, __shfl_xor(m, 32));
            float a0 = 0.f, a1 = 0.f, a2 = 0.f, a3 = 0.f;
            float a4 = 0.f, a5 = 0.f, a6 = 0.f, a7 = 0.f;
            for (int k = 0; k < m; k += 8) {
                int sb[8];
                #pragma unroll
                for (int j = 0; j < 8; ++j) {  // 8 LDS reads issue together
                    int kj = k + j;
                    sb[j] = (kj < cl) ? (int)srcs[rsl + kj] : -1;
                }
                #pragma unroll
                for (int j = 0; j < 8; ++j) {  // 8 row loads in flight
                    bool take = sb[j] >= 0;
                    int s = take ? sb[j] : 0;  // dummy hits node 0's cached row
                    uint4 v = yr4[(size_t)s * 8 + fl];
                    if (!take) { v.x = 0u; v.y = 0u; v.z = 0u; v.w = 0u; }
                    a0 += bf2f_lo(v.x); a1 += bf2f_hi(v.x);
                    a2 += bf2f_lo(v.y); a3 += bf2f_hi(v.y);
                    a4 += bf2f_lo(v.z); a5 += bf2f_hi(v.z);
                    a6 += bf2f_lo(v.w); a7 += bf2f_hi(v.w);
                }
            }
            if (valid) {
                float nt = nrmL[ln];
                size_t basei = (size_t)node * 16 + fl * 2;
                float4 r0, r1;
                if (c == 0) {
                    float4 xv0 = x4[basei], xv1 = x4[basei + 1];
                    r0.x = a0 * nt + EPS * xv0.x;  r0.y = a1 * nt + EPS * xv0.y;
                    r0.z = a2 * nt + EPS * xv0.z;  r0.w = a3 * nt + EPS * xv0.w;
                    r1.x = a4 * nt + EPS * xv1.x;  r1.y = a5 * nt + EPS * xv1.y;
                    r1.z = a6 * nt + EPS * xv1.z;  r1.w = a7 * nt + EPS * xv1.w;
                } else {                       // rare multi-chunk path: RMW
                    float4 p0 = out4[basei], p1 = out4[basei + 1];
                    r0.x = p0.x + a0 * nt;  r0.y = p0.y + a1 * nt;
                    r0.z = p0.z + a2 * nt;  r0.w = p0.w + a3 * nt;
                    r1.x = p1.x + a4 * nt;  r1.y = p1.y + a5 * nt;
                    r1.z = p1.z + a6 * nt;  r1.w = p1.w + a7 * nt;
                }
                out4[basei] = r0;              // coalesced: 32B/lane
                out4[basei + 1] = r1;
            }
        }
    }
}

// ---------------- tiny-ws / big-n fallback (round-1 proven) ----------------

__global__ void fb_hist(const int* __restrict__ src, int* __restrict__ deg, int E) {
    int e = blockIdx.x * blockDim.x + threadIdx.x;
    if (e < E) atomicAdd(&deg[src[e]], 1);
}
__global__ void fb_norm(const int* __restrict__ deg, float* __restrict__ norm, int n) {
    int i = blockIdx.x * blockDim.x + threadIdx.x;
    if (i < n) norm[i] = rsqrtf(fmaxf((float)deg[i], 1.0f));
}
__global__ void fb_init_out(const float4* __restrict__ x, float4* __restrict__ out, int n4) {
    int i = blockIdx.x * blockDim.x + threadIdx.x;
    if (i < n4) {
        float4 v = x[i];
        out[i] = make_float4(v.x * EPS, v.y * EPS, v.z * EPS, v.w * EPS);
    }
}
__global__ void fb_scatter(const float* __restrict__ x, const int* __restrict__ src,
                           const int* __restrict__ dst, const float* __restrict__ norm,
                           float* __restrict__ out, int E) {
    long long tid = (long long)blockIdx.x * blockDim.x + threadIdx.x;
    int e = (int)(tid >> 6), d = (int)(tid & 63);
    if (e < E) {
        int s = src[e], t = dst[e];
        atomicAdd(&out[(size_t)t * D + d], norm[s] * norm[t] * x[(size_t)s * D + d]);
    }
}

// ---------------- launcher ----------------

extern "C" void kernel_launch(void* const* d_in, const int* in_sizes, int n_in,
                              void* d_out, int out_size, void* d_ws, size_t ws_size,
                              hipStream_t stream) {
    const float* x   = (const float*)d_in[0];
    const int*   src = (const int*)d_in[1];
    const int*   dst = (const int*)d_in[2];
    float* out = (float*)d_out;

    const int ND = in_sizes[0];
    const int E  = in_sizes[1];
    const int n  = ND / D;
    const int NB   = (n + BKT - 1) / BKT;
    const int NBLK = (E + EPB - 1) / EPB;
    const int NBP  = NB + 1;
    constexpr int B = 256;

    // workspace layout (16B-aligned chunks)
    size_t off = 0;
    auto take = [&](size_t bytes) { size_t o = off; off = (off + bytes + 15) & ~15ull; return o; };
    size_t o_rec  = take((size_t)NBLK * EPB * 4);       // recB u32
    size_t o_srec = take((size_t)NBLK * EPB);           // srecB u8
    size_t o_tabD = take((size_t)NBLK * NBP * 2);       // tabD u16
    size_t o_tabS = take((size_t)NBLK * NBP * 2);       // tabS u16
    size_t o_yh   = take((size_t)ND * 2);               // yh u32 (bf16x2)
    size_t o_norm = take((size_t)n * 4);                // norm f32
    size_t need = off;

    if (NB <= NBMAX && NBLK <= MAXBLK && n < (1 << 24) && need <= ws_size && E > 0) {
        char* ws = (char*)d_ws;
        unsigned int*   recB  = (unsigned int*)(ws + o_rec);
        unsigned char*  srecB = (unsigned char*)(ws + o_srec);
        unsigned short* tabD  = (unsigned short*)(ws + o_tabD);
        unsigned short* tabS  = (unsigned short*)(ws + o_tabS);
        unsigned int*   yh    = (unsigned int*)(ws + o_yh);
        float*          norm  = (float*)(ws + o_norm);

        partition_kernel<<<NBLK, PTHREADS, 0, stream>>>(src, dst, recB, srecB,
                                                        tabD, tabS, E, NB, NBP);
        degnorm_kernel<<<NB, NTHREADS, 0, stream>>>(srecB, tabS, norm, n, NBLK, NBP);
        int yt = ND / 2;
        int yg = (yt + 255) / 256; if (yg > 2048) yg = 2048;
        yhconv_kernel<<<yg, 256, 0, stream>>>((const float2*)x, norm, yh, yt);
        sortgather_kernel<<<NB, GTHREADS, 0, stream>>>(recB, tabD, norm, (const uint4*)yh,
                                                       (const float4*)x, (float4*)out,
                                                       n, NBLK, NBP);
    } else {
        int*   deg  = (int*)d_ws;
        float* norm = (float*)d_ws + n;
        hipMemsetAsync(deg, 0, (size_t)n * sizeof(int), stream);
        fb_hist<<<(E + B - 1) / B, B, 0, stream>>>(src, deg, E);
        fb_norm<<<(n + B - 1) / B, B, 0, stream>>>(deg, norm, n);
        fb_init_out<<<(ND / 4 + B - 1) / B, B, 0, stream>>>((const float4*)x, (float4*)out, ND / 4);
        long long total = (long long)E * D;
        fb_scatter<<<(int)((total + B - 1) / B), B, 0, stream>>>(x, src, dst, norm, out, E);
    }
}

// Round 11
// 140.110 us; speedup vs baseline: 1.2125x; 1.1780x over previous
//
#include <hip/hip_runtime.h>

// GCN aggregation: out[t] = norm[t] * sum_{e:dst=t} norm[src]*x[src] + EPS*x[t]
// Round 20: revert to the round-13 architecture (best measured total: 140.7 us)
// and keep only the compatible later wins. Evidence: r13's sortgather (1024 thr,
// CONTIGUOUS per-bucket rec read) was <44 us; the per-block-region redesign
// (r14-r19) moved fragment assembly to sortgather's read side as ~25 us of
// serialized segment-table prologue -> 62-70 us, totals 165-180 vs 140.7.
// Partition scatters directly into shared per-bucket arrays (84B avg fragments,
// ~1.7x write amp on 8 MB - measured fine in r13) with 32-bit reserve atomics,
// no LDS staging, no register stash (re-read src/dst via int4).
// New win kept: normyh split into degnorm (hist+norm, NB blocks) + grid-strided
// yhconv (pure streaming at full HBM BW). 5 launches + 1 tiny memset.
constexpr int D        = 64;
constexpr float EPS    = 0.5f;
constexpr int BKT      = 256;    // nodes per bucket
constexpr int CAPB_MAX = 4096;
constexpr int EPB      = 8192;   // edges per partition block
constexpr int PTHREADS = 512;
constexpr int EPT      = EPB / PTHREADS;   // 16
constexpr int GTHREADS = 1024;   // sortgather block size (16 waves)
constexpr int NBMAX    = 512;    // max node buckets (n <= 131072)
constexpr int MAXOVF   = 65536;

__device__ __forceinline__ unsigned int f2bf(float f) {
    unsigned int u = __float_as_uint(f);
    return (u + 0x7FFFu + ((u >> 16) & 1u)) >> 16;   // RNE to bf16
}
__device__ __forceinline__ float bf2f_lo(unsigned int v) { return __uint_as_float(v << 16); }
__device__ __forceinline__ float bf2f_hi(unsigned int v) { return __uint_as_float(v & 0xFFFF0000u); }

// ---------------- main path ----------------

// Scatter edges into shared per-bucket arrays rec[b*capb..] (dst-bucketed,
// packed (s<<8)|(t&255)) and srec[b*capb..] (src-bucketed bytes). Per-
// (block,bucket) reserve via one global atomic; per-edge rank via LDS atomic.
// No LDS staging of the records themselves (4-8 KB LDS, 8 waves, no spill).
__global__ __launch_bounds__(PTHREADS)
void partition_kernel(const int* __restrict__ src, const int* __restrict__ dst,
                      int* __restrict__ curD, int* __restrict__ curS,
                      unsigned int* __restrict__ rec, unsigned char* __restrict__ srec,
                      int* __restrict__ ovf_cnt, int* __restrict__ ovf,
                      int* __restrict__ sovf_cnt, int* __restrict__ sovf,
                      int E, int NB, int capb) {
    __shared__ int histD[NBMAX];   // count, then rank
    __shared__ int histS[NBMAX];
    __shared__ int startD[NBMAX];
    __shared__ int startS[NBMAX];
    const int base = blockIdx.x * EPB;
    const int tid  = threadIdx.x;
    const bool full = (base + EPB) <= E;
    for (int b = tid; b < NB; b += PTHREADS) { histD[b] = 0; histS[b] = 0; }
    __syncthreads();

    // ---- pass 1: count ----
    if (full) {
        const int4* s4 = (const int4*)(src + base);
        const int4* d4 = (const int4*)(dst + base);
        #pragma unroll
        for (int k = 0; k < EPT / 4; ++k) {
            int4 sv = s4[tid + k * PTHREADS];
            int4 dv = d4[tid + k * PTHREADS];
            atomicAdd(&histD[dv.x >> 8], 1); atomicAdd(&histS[sv.x >> 8], 1);
            atomicAdd(&histD[dv.y >> 8], 1); atomicAdd(&histS[sv.y >> 8], 1);
            atomicAdd(&histD[dv.z >> 8], 1); atomicAdd(&histS[sv.z >> 8], 1);
            atomicAdd(&histD[dv.w >> 8], 1); atomicAdd(&histS[sv.w >> 8], 1);
        }
    } else {
        for (int k = 0; k < EPT; ++k) {
            int e = base + tid + k * PTHREADS;
            if (e < E) {
                atomicAdd(&histD[dst[e] >> 8], 1);
                atomicAdd(&histS[src[e] >> 8], 1);
            }
        }
    }
    __syncthreads();
    // ---- reserve: one global atomic per (block,bucket) ----
    for (int b = tid; b < NB; b += PTHREADS) {
        int c = histD[b];
        startD[b] = (c > 0) ? atomicAdd(&curD[b], c) : 0;
        histD[b] = 0;                          // reuse as rank
        int c2 = histS[b];
        startS[b] = (c2 > 0) ? atomicAdd(&curS[b], c2) : 0;
        histS[b] = 0;
    }
    __syncthreads();
    // ---- pass 2: place (re-read src/dst; L2-resident) ----
    if (full) {
        const int4* s4 = (const int4*)(src + base);
        const int4* d4 = (const int4*)(dst + base);
        #pragma unroll
        for (int k = 0; k < EPT / 4; ++k) {
            int4 sv = s4[tid + k * PTHREADS];
            int4 dv = d4[tid + k * PTHREADS];
            int ss[4] = {sv.x, sv.y, sv.z, sv.w};
            int tt[4] = {dv.x, dv.y, dv.z, dv.w};
            #pragma unroll
            for (int j = 0; j < 4; ++j) {
                int s = ss[j], t = tt[j];
                int bD = t >> 8;
                int r  = atomicAdd(&histD[bD], 1);
                int p  = startD[bD] + r;       // zero-based within bucket
                if (p < capb) {
                    rec[(size_t)bD * capb + p] = ((unsigned int)s << 8) | (unsigned int)(t & (BKT - 1));
                } else {
                    int i = atomicAdd(ovf_cnt, 1);
                    if (i < MAXOVF) { ovf[2 * i] = s; ovf[2 * i + 1] = t; }
                }
                int bS = s >> 8;
                int r2 = atomicAdd(&histS[bS], 1);
                int p2 = startS[bS] + r2;
                if (p2 < capb) {
                    srec[(size_t)bS * capb + p2] = (unsigned char)(s & (BKT - 1));
                } else {
                    int i = atomicAdd(sovf_cnt, 1);
                    if (i < MAXOVF) sovf[i] = s;
                }
            }
        }
    } else {
        for (int k = 0; k < EPT; ++k) {
            int e = base + tid + k * PTHREADS;
            if (e < E) {
                int s = src[e], t = dst[e];
                int bD = t >> 8;
                int r  = atomicAdd(&histD[bD], 1);
                int p  = startD[bD] + r;
                if (p < capb) {
                    rec[(size_t)bD * capb + p] = ((unsigned int)s << 8) | (unsigned int)(t & (BKT - 1));
                } else {
                    int i = atomicAdd(ovf_cnt, 1);
                    if (i < MAXOVF) { ovf[2 * i] = s; ovf[2 * i + 1] = t; }
                }
                int bS = s >> 8;
                int r2 = atomicAdd(&histS[bS], 1);
                int p2 = startS[bS] + r2;
                if (p2 < capb) {
                    srec[(size_t)bS * capb + p2] = (unsigned char)(s & (BKT - 1));
                } else {
                    int i = atomicAdd(sovf_cnt, 1);
                    if (i < MAXOVF) sovf[i] = s;
                }
            }
        }
    }
}

// Per-bucket out-degree histogram from CONTIGUOUS srec[b*capb..] -> norm[].
__global__ __launch_bounds__(256)
void degnorm_kernel(const unsigned char* __restrict__ srec, const int* __restrict__ curS,
                    const int* __restrict__ sovf_cnt, const int* __restrict__ sovf,
                    float* __restrict__ norm, int n, int capb) {
    const int b   = blockIdx.x;
    const int tid = threadIdx.x;
    __shared__ int hist[BKT];
    hist[tid] = 0;                             // BKT == blockDim == 256
    __syncthreads();
    int cnt = curS[b];
    if (cnt > capb) cnt = capb;
    const unsigned int* s4 = (const unsigned int*)(srec + (size_t)b * capb);  // capb % 4 == 0
    int nw = cnt >> 2;
    for (int i = tid; i < nw; i += 256) {      // word-wise coalesced
        unsigned int w = s4[i];
        atomicAdd(&hist[w & 255u], 1);
        atomicAdd(&hist[(w >> 8) & 255u], 1);
        atomicAdd(&hist[(w >> 16) & 255u], 1);
        atomicAdd(&hist[w >> 24], 1);
    }
    for (int i = (nw << 2) + tid; i < cnt; i += 256)
        atomicAdd(&hist[srec[(size_t)b * capb + i]], 1);
    int oc = *sovf_cnt;                        // expected 0
    if (oc > 0) {
        if (oc > MAXOVF) oc = MAXOVF;
        for (int i = tid; i < oc; i += 256) {
            int s = sovf[i];
            if ((s >> 8) == b) atomicAdd(&hist[s & (BKT - 1)], 1);
        }
    }
    __syncthreads();
    int node = b * BKT + tid;
    if (node < n) norm[node] = rsqrtf(fmaxf((float)hist[tid], 1.0f));
}

// Pure streaming: yh = bf16(norm * x). Grid-strided, full HBM bandwidth.
__global__ __launch_bounds__(256)
void yhconv_kernel(const float2* __restrict__ x2, const float* __restrict__ norm,
                   unsigned int* __restrict__ yh, int total) {
    int stride = gridDim.x * 256;
    for (int i = blockIdx.x * 256 + threadIdx.x; i < total; i += stride) {
        float2 v = x2[i];
        float nm = norm[i >> 5];               // 32 float2 per node; broadcast load
        yh[i] = f2bf(v.x * nm) | (f2bf(v.y * nm) << 16);
    }
}

// One block per bucket (1024 threads = 16 waves, ~39 KB LDS). CONTIGUOUS read
// of the bucket's records (coalesced, no segment tables), LDS counting sort to
// per-node src lists (shfl scan, 2 barriers), then gather yh rows: 8 nodes per
// wave (8 lanes x uint4 = 128B row), 8-deep unroll for MLP.
__global__ __launch_bounds__(GTHREADS)
void sortgather_kernel(const unsigned int* __restrict__ rec, const int* __restrict__ curD,
                       const float* __restrict__ norm, const uint4* __restrict__ yr4,
                       const float4* __restrict__ x4, float4* __restrict__ out4,
                       int n, int capb) {
    __shared__ unsigned int recs[CAPB_MAX];   // 16 KB
    __shared__ unsigned int srcs[CAPB_MAX];   // 16 KB
    __shared__ int hist[BKT];                 // per-node in-count (pristine after scan)
    __shared__ int rankb[BKT];
    __shared__ int rsL[BKT];                  // per-node exclusive start (pristine)
    __shared__ float nrmL[BKT];               // per-node dst norm
    __shared__ unsigned int wsums[GTHREADS / 64];
    const int b   = blockIdx.x;
    const int tid = threadIdx.x;
    const int lane = tid & 63;
    const int wid  = tid >> 6;

    int cnt = curD[b];
    if (cnt > capb) cnt = capb;
    for (int i = tid; i < cnt; i += GTHREADS) recs[i] = rec[(size_t)b * capb + i];
    if (tid < BKT) {
        hist[tid] = 0;
        int node = b * BKT + tid;
        nrmL[tid] = (node < n) ? norm[node] : 1.0f;
    }
    __syncthreads();
    for (int i = tid; i < cnt; i += GTHREADS) atomicAdd(&hist[recs[i] & (BKT - 1)], 1);
    __syncthreads();
    // ---- per-wave shfl inclusive scan over hist[0..BKT) (threads 0..255) ----
    {
        int v = (tid < BKT) ? hist[tid] : 0;
        #pragma unroll
        for (int off = 1; off < 64; off <<= 1) {
            int t = __shfl_up(v, off);
            if (lane >= off) v += t;
        }
        if (tid < BKT && lane == 63) wsums[wid] = (unsigned int)v;
        __syncthreads();
        if (tid < BKT) {
            int add = 0;
            #pragma unroll
            for (int w = 0; w < BKT / 64; ++w)
                if (w < wid) add += (int)wsums[w];
            int excl = v + add - hist[tid];
            rankb[tid] = excl;
            rsL[tid]   = excl;
        }
    }
    __syncthreads();
    for (int i = tid; i < cnt; i += GTHREADS) {
        unsigned int v = recs[i];
        int pos = atomicAdd(&rankb[v & (BKT - 1)], 1);
        srcs[pos] = v >> 8;
    }
    __syncthreads();

    // ---- gather phase: 16 waves x 8 nodes -> 128 nodes/round, 2 rounds ----
    const int fl  = lane & 7;                  // uint4 index within 128B row
    const int oct = lane >> 3;                 // node within 8-node group
    #pragma unroll
    for (int r = 0; r < BKT / 128; ++r) {
        int ln   = r * 128 + wid * 8 + oct;    // local node 0..255
        int node = b * BKT + ln;
        bool valid = node < n;
        int rsl = valid ? rsL[ln]  : 0;
        int cl  = valid ? hist[ln] : 0;
        int m = cl;                            // uniform loop count = wave-max
        m = max(m, __shfl_xor(m, 8));
        m = max(m, __shfl_xor(m, 16));
        m = max(m, __shfl_xor(m, 32));
        float a0 = 0.f, a1 = 0.f, a2 = 0.f, a3 = 0.f;
        float a4 = 0.f, a5 = 0.f, a6 = 0.f, a7 = 0.f;
        for (int k = 0; k < m; k += 8) {
            int sb[8];
            #pragma unroll
            for (int j = 0; j < 8; ++j) {      // 8 LDS reads issue together
                int kj = k + j;
                sb[j] = (kj < cl) ? (int)srcs[rsl + kj] : -1;
            }
            #pragma unroll
            for (int j = 0; j < 8; ++j) {      // 8 row loads in flight
                bool take = sb[j] >= 0;
                int s = take ? sb[j] : 0;      // dummy hits node 0's cached row
                uint4 v = yr4[(size_t)s * 8 + fl];
                if (!take) { v.x = 0u; v.y = 0u; v.z = 0u; v.w = 0u; }
                a0 += bf2f_lo(v.x); a1 += bf2f_hi(v.x);
                a2 += bf2f_lo(v.y); a3 += bf2f_hi(v.y);
                a4 += bf2f_lo(v.z); a5 += bf2f_hi(v.z);
                a6 += bf2f_lo(v.w); a7 += bf2f_hi(v.w);
            }
        }
        if (valid) {
            float nt = nrmL[ln];
            size_t basei = (size_t)node * 16 + fl * 2;
            float4 xv0 = x4[basei], xv1 = x4[basei + 1];
            float4 r0, r1;
            r0.x = a0 * nt + EPS * xv0.x;  r0.y = a1 * nt + EPS * xv0.y;
            r0.z = a2 * nt + EPS * xv0.z;  r0.w = a3 * nt + EPS * xv0.w;
            r1.x = a4 * nt + EPS * xv1.x;  r1.y = a5 * nt + EPS * xv1.y;
            r1.z = a6 * nt + EPS * xv1.z;  r1.w = a7 * nt + EPS * xv1.w;
            out4[basei] = r0;              // coalesced: 32B/lane
            out4[basei + 1] = r1;
        }
    }
}

// rare: dst-bucket overflow edges (expected 0)
__global__ void cleanup_kernel(const float* __restrict__ x, const float* __restrict__ norm,
                               const int* __restrict__ ovf_cnt, const int* __restrict__ ovf,
                               float* __restrict__ out) {
    int cnt = *ovf_cnt;
    if (cnt > MAXOVF) cnt = MAXOVF;
    long long total = (long long)cnt * D;
    long long stride = (long long)gridDim.x * blockDim.x;
    for (long long i = blockIdx.x * (long long)blockDim.x + threadIdx.x; i < total; i += stride) {
        int e = (int)(i >> 6), d = (int)(i & 63);
        int s = ovf[2 * e], t = ovf[2 * e + 1];
        atomicAdd(&out[(size_t)t * D + d], norm[s] * norm[t] * x[(size_t)s * D + d]);
    }
}

// ---------------- tiny-ws / big-n fallback (round-1 proven) ----------------

__global__ void fb_hist(const int* __restrict__ src, int* __restrict__ deg, int E) {
    int e = blockIdx.x * blockDim.x + threadIdx.x;
    if (e < E) atomicAdd(&deg[src[e]], 1);
}
__global__ void fb_norm(const int* __restrict__ deg, float* __restrict__ norm, int n) {
    int i = blockIdx.x * blockDim.x + threadIdx.x;
    if (i < n) norm[i] = rsqrtf(fmaxf((float)deg[i], 1.0f));
}
__global__ void fb_init_out(const float4* __restrict__ x, float4* __restrict__ out, int n4) {
    int i = blockIdx.x * blockDim.x + threadIdx.x;
    if (i < n4) {
        float4 v = x[i];
        out[i] = make_float4(v.x * EPS, v.y * EPS, v.z * EPS, v.w * EPS);
    }
}
__global__ void fb_scatter(const float* __restrict__ x, const int* __restrict__ src,
                           const int* __restrict__ dst, const float* __restrict__ norm,
                           float* __restrict__ out, int E) {
    long long tid = (long long)blockIdx.x * blockDim.x + threadIdx.x;
    int e = (int)(tid >> 6), d = (int)(tid & 63);
    if (e < E) {
        int s = src[e], t = dst[e];
        atomicAdd(&out[(size_t)t * D + d], norm[s] * norm[t] * x[(size_t)s * D + d]);
    }
}

// ---------------- launcher ----------------

extern "C" void kernel_launch(void* const* d_in, const int* in_sizes, int n_in,
                              void* d_out, int out_size, void* d_ws, size_t ws_size,
                              hipStream_t stream) {
    const float* x   = (const float*)d_in[0];
    const int*   src = (const int*)d_in[1];
    const int*   dst = (const int*)d_in[2];
    float* out = (float*)d_out;

    const int ND = in_sizes[0];
    const int E  = in_sizes[1];
    const int n  = ND / D;
    const int NB = (n + BKT - 1) / BKT;
    constexpr int B = 256;
    const int NB64 = (NB + 63) & ~63;

    int capb = 0;
    for (int c : {4096, 3584}) {               // divisible by 16
        size_t srecB = ((size_t)NB * c + 15) & ~15ull;
        size_t need = (size_t)NB * c * 4                // rec (packed u32)
                    + srecB                             // srec (u8)
                    + (size_t)ND * 2                    // yh
                    + (size_t)n * 4                     // norm
                    + (size_t)(2 * NB64 + 128) * 4      // curD, curS, ovf_cnt, sovf_cnt
                    + (size_t)3 * MAXOVF * 4;           // ovf + sovf
        if (need <= ws_size) { capb = c; break; }
    }

    if (NB <= NBMAX && capb > 0 && n < (1 << 24) && E > 0) {
        unsigned int* rec   = (unsigned int*)d_ws;                        // NB*capb u32
        unsigned char* srec = (unsigned char*)(rec + (size_t)NB * capb);  // NB*capb u8
        size_t srecB        = ((size_t)NB * capb + 15) & ~15ull;
        unsigned int* yh    = (unsigned int*)(srec + srecB);              // ND/2 u32
        float* norm         = (float*)(yh + ND / 2);                      // n
        int* curD           = (int*)(norm + n);                           // NB64
        int* curS           = curD + NB64;                                // NB64
        int* ovf_cnt        = curS + NB64;                                // 64
        int* sovf_cnt       = ovf_cnt + 64;                               // 64
        int* ovf            = sovf_cnt + 64;                              // 2*MAXOVF
        int* sovf           = ovf + 2 * MAXOVF;                           // MAXOVF

        // curD + curS + ovf_cnt + sovf_cnt zeroed in one DMA memset
        hipMemsetAsync(curD, 0, (size_t)(2 * NB64 + 128) * 4, stream);
        partition_kernel<<<(E + EPB - 1) / EPB, PTHREADS, 0, stream>>>(src, dst, curD, curS,
                                                                       rec, srec, ovf_cnt, ovf,
                                                                       sovf_cnt, sovf, E, NB, capb);
        degnorm_kernel<<<NB, B, 0, stream>>>(srec, curS, sovf_cnt, sovf, norm, n, capb);
        int yt = ND / 2;
        int yg = (yt + 255) / 256; if (yg > 2048) yg = 2048;
        yhconv_kernel<<<yg, B, 0, stream>>>((const float2*)x, norm, yh, yt);
        sortgather_kernel<<<NB, GTHREADS, 0, stream>>>(rec, curD, norm, (const uint4*)yh,
                                                       (const float4*)x, (float4*)out, n, capb);
        cleanup_kernel<<<32, B, 0, stream>>>(x, norm, ovf_cnt, ovf, out);
    } else {
        int*   deg  = (int*)d_ws;
        float* norm = (float*)d_ws + n;
        hipMemsetAsync(deg, 0, (size_t)n * sizeof(int), stream);
        fb_hist<<<(E + B - 1) / B, B, 0, stream>>>(src, deg, E);
        fb_norm<<<(n + B - 1) / B, B, 0, stream>>>(deg, norm, n);
        fb_init_out<<<(ND / 4 + B - 1) / B, B, 0, stream>>>((const float4*)x, (float4*)out, ND / 4);
        long long total = (long long)E * D;
        fb_scatter<<<(int)((total + B - 1) / B), B, 0, stream>>>(x, src, dst, norm, out, E);
    }
}